// Round 11
// baseline (459.357 us; speedup 1.0000x reference)
//
#include <hip/hip_runtime.h>
#include <stdint.h>
#include <math.h>

#define BATCH 2
#define SEQ 2048
#define DM 2048
#define NH 16
#define HD 128

typedef unsigned short u16;
typedef __attribute__((ext_vector_type(8))) __bf16 bf16x8;
typedef __attribute__((ext_vector_type(8))) _Float16 f16x8;
typedef __attribute__((ext_vector_type(4))) float f32x4;
typedef __attribute__((ext_vector_type(4))) unsigned short u16x4;

__device__ inline float bf2f(u16 x) {
    return __uint_as_float(((unsigned)x) << 16);
}
__device__ inline u16 f2bf(float f) {
    unsigned u = __float_as_uint(f);
    return (u16)((u + 0x7FFF + ((u >> 16) & 1)) >> 16);
}
__device__ inline u16 f2h(float f) {
    union { _Float16 h; u16 u; } c;
    c.h = (_Float16)f;
    return c.u;
}
__device__ inline f32x4 mfma16(bf16x8 a, bf16x8 b, f32x4 c) {
    return __builtin_amdgcn_mfma_f32_16x16x32_bf16(a, b, c, 0, 0, 0);
}
__device__ inline f32x4 mfma16h(f16x8 a, f16x8 b, f32x4 c) {
    return __builtin_amdgcn_mfma_f32_16x16x32_f16(a, b, c, 0, 0, 0);
}
// async global->LDS, 16B per lane. Dest must be wave-uniform base + lane*16
// (HW semantics, m104); our staging index satisfies this by construction.
__device__ inline void cp16(const u16* g, u16* l) {
    __builtin_amdgcn_global_load_lds(
        (const __attribute__((address_space(1))) unsigned int*)g,
        (__attribute__((address_space(3))) unsigned int*)l, 16, 0, 0);
}

// ---------------- prep: 4x W transpose (fp32->bf16) + X cast, one launch ----
// grid (64, 64, 5): z<4 -> transpose weight z; z==4 -> xcast chunk.
__global__ __launch_bounds__(256) void prep(const float* __restrict__ Wq,
                                            const float* __restrict__ Wk,
                                            const float* __restrict__ Wv,
                                            const float* __restrict__ Wo,
                                            const float* __restrict__ X,
                                            u16* __restrict__ WqT,
                                            u16* __restrict__ WkT,
                                            u16* __restrict__ WvT,
                                            u16* __restrict__ WoT,
                                            u16* __restrict__ Xb) {
    __shared__ u16 tile[32][33];
    if (blockIdx.z == 4) {
        long bi = (long)blockIdx.y * 64 + blockIdx.x;
        long i = (bi * 256 + threadIdx.x) * 8;
        float4 v0 = *(const float4*)&X[i];
        float4 v1 = *(const float4*)&X[i + 4];
        union { uint4 q; u16 e[8]; } u;
        u.e[0] = f2bf(v0.x); u.e[1] = f2bf(v0.y);
        u.e[2] = f2bf(v0.z); u.e[3] = f2bf(v0.w);
        u.e[4] = f2bf(v1.x); u.e[5] = f2bf(v1.y);
        u.e[6] = f2bf(v1.z); u.e[7] = f2bf(v1.w);
        *(uint4*)&Xb[i] = u.q;
        return;
    }
    const float* src; u16* dst;
    switch (blockIdx.z) {
        case 0: src = Wq; dst = WqT; break;
        case 1: src = Wk; dst = WkT; break;
        case 2: src = Wv; dst = WvT; break;
        default: src = Wo; dst = WoT; break;
    }
    int bx = blockIdx.x * 32, by = blockIdx.y * 32;
    int tx = threadIdx.x & 31, ty = threadIdx.x >> 5;  // ty in 0..7
    #pragma unroll
    for (int i = 0; i < 32; i += 8)
        tile[ty + i][tx] = f2bf(src[(long)(by + ty + i) * DM + bx + tx]);
    __syncthreads();
    #pragma unroll
    for (int i = 0; i < 32; i += 8)
        dst[(long)(bx + ty + i) * DM + by + tx] = tile[tx][ty + i];
}

#define BM 128
#define BN 128
#define BK 64

// GEMM staging/compute shared macro (flat, no templates/lambdas — R8/R9's
// templated core coincided with two container deaths; flat R10 version ran).
// Pipeline: double-buffered LDS + prefetch-next-before-compute, one
// vmcnt-draining __syncthreads per tile (T3 minimum recipe).
// Swizzle (rule #21): linear gload_lds dest, inverse-swizzled global
// SOURCE column, same XOR on the ds_read slot -> 2 lanes/bank = free
// (verified R10: SQ_LDS_BANK_CONFLICT 3.8e7 -> 0).
#define GEMM_PRE(Aptr, aR0, Bptr, bR0, Kdim)                                  \
    __shared__ alignas(16) u16 As[2][BM * BK];                                \
    __shared__ alignas(16) u16 Bs[2][BM * BK];                                \
    int tid = threadIdx.x;                                                    \
    int lane = tid & 63;                                                      \
    int quad = lane >> 4, l16 = lane & 15;                                    \
    int wm = (tid >> 6) & 1, wn = tid >> 7;                                   \
    const u16* aSrc[4];                                                       \
    const u16* bSrc[4];                                                       \
    int ldst[4];                                                              \
    for (int p = 0; p < 4; p++) {                                             \
        int idx = (p << 8) + tid;                                             \
        int r = idx >> 3, sl = idx & 7;                                       \
        int sc = (sl ^ (r & 7)) << 3;                                         \
        aSrc[p] = &(Aptr)[((aR0) + r) * (Kdim) + sc];                         \
        bSrc[p] = &(Bptr)[((bR0) + r) * (Kdim) + sc];                         \
        ldst[p] = idx << 3;                                                   \
    }                                                                         \
    f32x4 acc[4][4];                                                          \
    for (int i = 0; i < 4; i++)                                               \
        for (int j = 0; j < 4; j++) acc[i][j] = (f32x4){0.f, 0.f, 0.f, 0.f};  \
    for (int p = 0; p < 4; p++) {                                             \
        cp16(aSrc[p], &As[0][ldst[p]]);                                       \
        cp16(bSrc[p], &Bs[0][ldst[p]]);                                       \
        aSrc[p] += BK; bSrc[p] += BK;                                         \
    }                                                                         \
    __syncthreads();                                                          \
    int NT = (Kdim) / BK;                                                     \
    int cur = 0;                                                              \
    for (int t = 0; t < NT; ++t) {                                            \
        if (t + 1 < NT) {                                                     \
            for (int p = 0; p < 4; p++) {                                     \
                cp16(aSrc[p], &As[cur ^ 1][ldst[p]]);                         \
                cp16(bSrc[p], &Bs[cur ^ 1][ldst[p]]);                         \
                aSrc[p] += BK; bSrc[p] += BK;                                 \
            }                                                                 \
        }                                                                     \
        _Pragma("unroll")                                                     \
        for (int kk = 0; kk < 2; kk++) {                                      \
            int sA = ((kk * 4 + quad) ^ (l16 & 7)) << 3;                      \
            bf16x8 af[4], bfr[4];                                             \
            _Pragma("unroll")                                                 \
            for (int i = 0; i < 4; i++)                                       \
                af[i] = *(const bf16x8*)&As[cur][(wm * 64 + i * 16 + l16) * 64 + sA]; \
            _Pragma("unroll")                                                 \
            for (int j = 0; j < 4; j++)                                       \
                bfr[j] = *(const bf16x8*)&Bs[cur][(wn * 64 + j * 16 + l16) * 64 + sA]; \
            _Pragma("unroll")                                                 \
            for (int i = 0; i < 4; i++)                                       \
                _Pragma("unroll")                                             \
                for (int j = 0; j < 4; j++)                                   \
                    acc[i][j] = mfma16(af[i], bfr[j], acc[i][j]);             \
        }                                                                     \
        __syncthreads();                                                      \
        cur ^= 1;                                                             \
    }

// ---------------- fused QKV GEMM: one launch, grid (48, 32) -----------------
// B = [WqT; WkT; WvT] stacked (6144x2048). mat: 0->Qb, 1->Kb, 2->Vt (f16,
// per-head transposed [b][h][d][s]).
__global__ __launch_bounds__(256) void gemm_qkv(const u16* __restrict__ A,
                                                const u16* __restrict__ Wcat,
                                                u16* __restrict__ Qb,
                                                u16* __restrict__ Kb,
                                                u16* __restrict__ Vt) {
    long rowBase = (long)blockIdx.y * BM;
    long colG = (long)blockIdx.x * BN;   // 0..6143
    int mat = (int)(colG >> 11);
    long colBase = colG & (DM - 1);
    GEMM_PRE(A, rowBase, Wcat, colG, DM)
    #pragma unroll
    for (int i = 0; i < 4; i++) {
        #pragma unroll
        for (int j = 0; j < 4; j++) {
            long col = colBase + wn * 64 + j * 16 + l16;
            if (mat == 2) {
                long row0 = rowBase + wm * 64 + i * 16 + quad * 4;
                long bb = row0 >> 11, ss = row0 & (SEQ - 1);
                long hh = col >> 7, dd = col & (HD - 1);
                u16x4 pk;
                #pragma unroll
                for (int r = 0; r < 4; r++) pk[r] = f2h(acc[i][j][r]);
                *(u16x4*)&Vt[(((bb * NH) + hh) * HD + dd) * SEQ + ss] = pk;
            } else {
                u16* C = (mat == 0) ? Qb : Kb;
                #pragma unroll
                for (int r = 0; r < 4; r++) {
                    long row = rowBase + wm * 64 + i * 16 + quad * 4 + r;
                    C[row * DM + col] = f2bf(acc[i][j][r]);
                }
            }
        }
    }
}

// ---------------- final GEMM: out(fp32) = Attn(bf16) * WoT^T ----------------
__global__ __launch_bounds__(256) void gemm_out(const u16* __restrict__ A,
                                                const u16* __restrict__ Bt,
                                                float* __restrict__ C) {
    long rowBase = (long)blockIdx.y * BM;
    long colBase = (long)blockIdx.x * BN;
    GEMM_PRE(A, rowBase, Bt, colBase, DM)
    #pragma unroll
    for (int i = 0; i < 4; i++)
        #pragma unroll
        for (int j = 0; j < 4; j++) {
            long col = colBase + wn * 64 + j * 16 + l16;
            #pragma unroll
            for (int r = 0; r < 4; r++) {
                long row = rowBase + wm * 64 + i * 16 + quad * 4 + r;
                C[row * DM + col] = acc[i][j][r];
            }
        }
}

// ---------------- RoPE (in-place on Q and K), fp32 fast trig ----------------
__global__ __launch_bounds__(256) void rope_kernel(u16* __restrict__ Q,
                                                   u16* __restrict__ Kb,
                                                   const int* __restrict__ pid) {
    int idx = blockIdx.x * blockDim.x + threadIdx.x;  // (m, h, d<64)
    int d = idx & 63;
    int h = (idx >> 6) & (NH - 1);
    int m = idx >> 10;  // 0..B*S-1
    int b = m >> 11, s = m & (SEQ - 1);
    int pos = pid[b * SEQ + s];
    float invf = __builtin_amdgcn_exp2f(-(float)d * 0.20762050593046015f);  // log2(10000)/64
    float freq = (float)pos * invf;
    float sn = __sinf(freq);
    float cs = __cosf(freq);
    long base = (long)m * DM + h * HD + d;
    float x1 = bf2f(Q[base]), x2 = bf2f(Q[base + 64]);
    Q[base] = f2bf(x1 * cs - x2 * sn);
    Q[base + 64] = f2bf(x2 * cs + x1 * sn);
    float y1 = bf2f(Kb[base]), y2 = bf2f(Kb[base + 64]);
    Kb[base] = f2bf(y1 * cs - y2 * sn);
    Kb[base + 64] = f2bf(y2 * cs + y1 * sn);
}

// ---------------- MFMA flash attention, kv-split-4 --------------------------
// Grid: (BATCH*NH, SEQ/32), 256-thread blocks (4 waves). All 4 waves own the
// SAME 32 q rows; kv tiles (64 wide) dealt t = w, w+4, ... Makespan of the
// heaviest block drops 17 -> 9 tiles; 8192 waves total. Fixed-offset softmax
// keeps partials ADDITIVE; combine = sequential LDS summation (src=1..3,
// one shared buffer, R10-proven pattern). NO min-waves clause (R6 lesson:
// forcing occupancy capped VGPR at 64 -> 0.9 GB spill). s_setprio around
// MFMA clusters (T5, m191).
__global__ __launch_bounds__(256) void attn_mfma(const u16* __restrict__ Q,
                                                 const u16* __restrict__ K,
                                                 const u16* __restrict__ Vt,
                                                 const int* __restrict__ amask,
                                                 u16* __restrict__ O) {
    // smem: per-wave P tiles (4 x 4608 B = 18432) overlaid after the loop by
    // combine buffers: of_lds 64 lanes x 68 f32 (17408 B) + ls 2048 B.
    __shared__ alignas(16) char smem[19456];
    int tid = threadIdx.x;
    int w = tid >> 6, lane = tid & 63;
    int quad = lane >> 4, l16 = lane & 15;
    int bh = blockIdx.x;
    int qblk = gridDim.y - 1 - blockIdx.y;  // heavy blocks first
    int b = bh >> 4, h = bh & (NH - 1);
    int qbase = qblk * 32;
    long head = (long)b * SEQ * DM + (long)h * HD;
    const u16* Vh = Vt + (long)bh * HD * SEQ;
    const int* mrow = amask + b * SEQ;
    u16* Pw = (u16*)smem + w * (32 * 72);

    bf16x8 qf[2][4];
    #pragma unroll
    for (int i = 0; i < 2; i++)
        #pragma unroll
        for (int kk = 0; kk < 4; kk++)
            qf[i][kk] = *(const bf16x8*)&Q[head + (long)(qbase + i * 16 + l16) * DM + kk * 32 + quad * 8];

    f32x4 of[2][8];
    #pragma unroll
    for (int i = 0; i < 2; i++)
        #pragma unroll
        for (int j = 0; j < 8; j++) of[i][j] = (f32x4){0.f, 0.f, 0.f, 0.f};
    float lsum[2][4] = {{0.f, 0.f, 0.f, 0.f}, {0.f, 0.f, 0.f, 0.f}};
    const float k2 = 0.12752792143808157f;   // (1/sqrt(128)) * log2(e)
    const float C2 = 7.213475204444817f;     // 5 * log2(e)

    int ntiles = (qbase + 32 + 63) >> 6;  // ceil((qbase+32)/64)
    for (int t = w; t < ntiles; t += 4) {
        int kv0 = t << 6;
        bf16x8 kf[16];
        #pragma unroll
        for (int half = 0; half < 4; half++)
            #pragma unroll
            for (int kk = 0; kk < 4; kk++)
                kf[half * 4 + kk] = *(const bf16x8*)&K[head + (long)(kv0 + half * 16 + l16) * DM + kk * 32 + quad * 8];
        int am[4];
        #pragma unroll
        for (int half = 0; half < 4; half++) am[half] = mrow[kv0 + half * 16 + l16];
        f32x4 sacc[2][4];
        #pragma unroll
        for (int i = 0; i < 2; i++)
            #pragma unroll
            for (int half = 0; half < 4; half++) sacc[i][half] = (f32x4){0.f, 0.f, 0.f, 0.f};
        __builtin_amdgcn_s_setprio(1);
        #pragma unroll
        for (int half = 0; half < 4; half++)
            #pragma unroll
            for (int kk = 0; kk < 4; kk++) {
                sacc[0][half] = mfma16(qf[0][kk], kf[half * 4 + kk], sacc[0][half]);
                sacc[1][half] = mfma16(qf[1][kk], kf[half * 4 + kk], sacc[1][half]);
            }
        __builtin_amdgcn_s_setprio(0);
        #pragma unroll
        for (int i = 0; i < 2; i++)
            #pragma unroll
            for (int half = 0; half < 4; half++) {
                int kvc = kv0 + half * 16 + l16;
                #pragma unroll
                for (int r = 0; r < 4; r++) {
                    int qr = qbase + i * 16 + quad * 4 + r;
                    float p = (kvc <= qr && am[half] > 0)
                                  ? __builtin_amdgcn_exp2f(sacc[i][half][r] * k2 - C2) : 0.f;
                    lsum[i][r] += p;
                    Pw[(i * 16 + quad * 4 + r) * 72 + half * 16 + l16] = f2h(p);
                }
            }
        f16x8 pf[2][2];
        #pragma unroll
        for (int i = 0; i < 2; i++)
            #pragma unroll
            for (int c = 0; c < 2; c++)
                pf[i][c] = *(const f16x8*)&Pw[(i * 16 + l16) * 72 + c * 32 + quad * 8];
        __builtin_amdgcn_s_setprio(1);
        #pragma unroll
        for (int c = 0; c < 2; c++)
            #pragma unroll
            for (int j = 0; j < 8; j++) {
                f16x8 vf = *(const f16x8*)&Vh[(long)(j * 16 + l16) * SEQ + kv0 + c * 32 + quad * 8];
                of[0][j] = mfma16h(pf[0][c], vf, of[0][j]);
                of[1][j] = mfma16h(pf[1][c], vf, of[1][j]);
            }
        __builtin_amdgcn_s_setprio(0);
    }
    // ---- combine the four waves' additive partials (sequential, 1 buffer) --
    __syncthreads();  // all waves done with Pw (LDS about to be reused)
    float* of_lds = (float*)smem;
    float* ls_lds = (float*)(smem + 17408);
    for (int src = 1; src < 4; ++src) {
        if (w == src) {
            #pragma unroll
            for (int i = 0; i < 2; i++)
                #pragma unroll
                for (int j = 0; j < 8; j++)
                    *(f32x4*)&of_lds[lane * 68 + (i * 8 + j) * 4] = of[i][j];
            #pragma unroll
            for (int i = 0; i < 2; i++)
                #pragma unroll
                for (int r = 0; r < 4; r++) ls_lds[lane * 8 + i * 4 + r] = lsum[i][r];
        }
        __syncthreads();
        if (w == 0) {
            #pragma unroll
            for (int i = 0; i < 2; i++)
                #pragma unroll
                for (int j = 0; j < 8; j++) {
                    f32x4 v = *(const f32x4*)&of_lds[lane * 68 + (i * 8 + j) * 4];
                    of[i][j] += v;
                }
            #pragma unroll
            for (int i = 0; i < 2; i++)
                #pragma unroll
                for (int r = 0; r < 4; r++) lsum[i][r] += ls_lds[lane * 8 + i * 4 + r];
        }
        __syncthreads();
    }
    if (w == 0) {
        #pragma unroll
        for (int i = 0; i < 2; i++) {
            float inv[4];
            #pragma unroll
            for (int r = 0; r < 4; r++) {
                float s = lsum[i][r];
                s += __shfl_xor(s, 1, 64);
                s += __shfl_xor(s, 2, 64);
                s += __shfl_xor(s, 4, 64);
                s += __shfl_xor(s, 8, 64);
                inv[r] = 1.0f / s;
            }
            #pragma unroll
            for (int j = 0; j < 8; j++)
                #pragma unroll
                for (int r = 0; r < 4; r++)
                    O[head + (long)(qbase + i * 16 + quad * 4 + r) * DM + j * 16 + l16] =
                        f2bf(of[i][j][r] * inv[r]);
        }
    }
}

extern "C" void kernel_launch(void* const* d_in, const int* in_sizes, int n_in,
                              void* d_out, int out_size, void* d_ws, size_t ws_size,
                              hipStream_t stream) {
    const float* X  = (const float*)d_in[0];
    const int* am   = (const int*)d_in[1];
    const int* pid  = (const int*)d_in[2];
    const float* Wq = (const float*)d_in[3];
    const float* Wk = (const float*)d_in[4];
    const float* Wv = (const float*)d_in[5];
    const float* Wo = (const float*)d_in[6];
    float* out = (float*)d_out;  // fp32 output, 32 MB

    // Workspace, 64 MB:
    //   [ 0- 8) WoT   [ 8-16) WqT   [16-24) WkT   [24-32) WvT  (contiguous
    //   stack = 6144x2048 B matrix for the fused QKV gemm)
    //   [32-48) Qb (attn output in-place)   [48-64) Kb
    // d_out (32 MB) doubles as scratch until the final gemm:
    //   Xb (bf16 X) at d_out[0:16MB); Vt (f16 [B][H][HD][S]) at [16:32MB).
    char* ws = (char*)d_ws;
    const size_t MB = 1024 * 1024;
    u16* WoT = (u16*)(ws + 0 * MB);
    u16* WqT = (u16*)(ws + 8 * MB);   // Wcat base (WkT, WvT follow)
    u16* WkT = (u16*)(ws + 16 * MB);
    u16* WvT = (u16*)(ws + 24 * MB);
    u16* Qb  = (u16*)(ws + 32 * MB);
    u16* Kb  = (u16*)(ws + 48 * MB);
    u16* Xb  = (u16*)d_out;
    u16* Vt  = (u16*)((char*)d_out + 16 * MB);

    dim3 tb(256);
    prep<<<dim3(64, 64, 5), tb, 0, stream>>>(Wq, Wk, Wv, Wo, X, WqT, WkT, WvT, WoT, Xb);

    gemm_qkv<<<dim3(3 * DM / BN, (BATCH * SEQ) / BM), tb, 0, stream>>>(Xb, WqT, Qb, Kb, Vt);

    int nrope = BATCH * SEQ * NH * 64;
    rope_kernel<<<nrope / 256, tb, 0, stream>>>(Qb, Kb, pid);

    dim3 ag(BATCH * NH, SEQ / 32);  // (32, 64): 2048 four-wave blocks
    attn_mfma<<<ag, tb, 0, stream>>>(Qb, Kb, Vt, am, Qb);  // O in-place

    gemm_out<<<dim3(DM / BN, (BATCH * SEQ) / BM), tb, 0, stream>>>(Qb, WoT, out);
}

// Round 12
// 441.306 us; speedup vs baseline: 1.0409x; 1.0409x over previous
//
#include <hip/hip_runtime.h>
#include <stdint.h>
#include <math.h>

#define BATCH 2
#define SEQ 2048
#define DM 2048
#define NH 16
#define HD 128

typedef unsigned short u16;
typedef __attribute__((ext_vector_type(8))) __bf16 bf16x8;
typedef __attribute__((ext_vector_type(8))) _Float16 f16x8;
typedef __attribute__((ext_vector_type(4))) float f32x4;
typedef __attribute__((ext_vector_type(4))) unsigned short u16x4;

__device__ inline float bf2f(u16 x) {
    return __uint_as_float(((unsigned)x) << 16);
}
__device__ inline u16 f2bf(float f) {
    unsigned u = __float_as_uint(f);
    return (u16)((u + 0x7FFF + ((u >> 16) & 1)) >> 16);
}
__device__ inline u16 f2h(float f) {
    union { _Float16 h; u16 u; } c;
    c.h = (_Float16)f;
    return c.u;
}
__device__ inline f32x4 mfma16(bf16x8 a, bf16x8 b, f32x4 c) {
    return __builtin_amdgcn_mfma_f32_16x16x32_bf16(a, b, c, 0, 0, 0);
}
__device__ inline f32x4 mfma16h(f16x8 a, f16x8 b, f32x4 c) {
    return __builtin_amdgcn_mfma_f32_16x16x32_f16(a, b, c, 0, 0, 0);
}
// async global->LDS, 16B per lane. Dest must be wave-uniform base + lane*16
// (HW semantics, m104); our staging index satisfies this by construction.
__device__ inline void cp16(const u16* g, u16* l) {
    __builtin_amdgcn_global_load_lds(
        (const __attribute__((address_space(1))) unsigned int*)g,
        (__attribute__((address_space(3))) unsigned int*)l, 16, 0, 0);
}

// ---------------- prep: 4x W transpose (fp32->bf16) + X cast, one launch ----
// grid (64, 64, 5): z<4 -> transpose weight z; z==4 -> xcast chunk.
__global__ __launch_bounds__(256) void prep(const float* __restrict__ Wq,
                                            const float* __restrict__ Wk,
                                            const float* __restrict__ Wv,
                                            const float* __restrict__ Wo,
                                            const float* __restrict__ X,
                                            u16* __restrict__ WqT,
                                            u16* __restrict__ WkT,
                                            u16* __restrict__ WvT,
                                            u16* __restrict__ WoT,
                                            u16* __restrict__ Xb) {
    __shared__ u16 tile[32][33];
    if (blockIdx.z == 4) {
        long bi = (long)blockIdx.y * 64 + blockIdx.x;
        long i = (bi * 256 + threadIdx.x) * 8;
        float4 v0 = *(const float4*)&X[i];
        float4 v1 = *(const float4*)&X[i + 4];
        union { uint4 q; u16 e[8]; } u;
        u.e[0] = f2bf(v0.x); u.e[1] = f2bf(v0.y);
        u.e[2] = f2bf(v0.z); u.e[3] = f2bf(v0.w);
        u.e[4] = f2bf(v1.x); u.e[5] = f2bf(v1.y);
        u.e[6] = f2bf(v1.z); u.e[7] = f2bf(v1.w);
        *(uint4*)&Xb[i] = u.q;
        return;
    }
    const float* src; u16* dst;
    switch (blockIdx.z) {
        case 0: src = Wq; dst = WqT; break;
        case 1: src = Wk; dst = WkT; break;
        case 2: src = Wv; dst = WvT; break;
        default: src = Wo; dst = WoT; break;
    }
    int bx = blockIdx.x * 32, by = blockIdx.y * 32;
    int tx = threadIdx.x & 31, ty = threadIdx.x >> 5;  // ty in 0..7
    #pragma unroll
    for (int i = 0; i < 32; i += 8)
        tile[ty + i][tx] = f2bf(src[(long)(by + ty + i) * DM + bx + tx]);
    __syncthreads();
    #pragma unroll
    for (int i = 0; i < 32; i += 8)
        dst[(long)(bx + ty + i) * DM + by + tx] = tile[tx][ty + i];
}

#define BM 128
#define BN 128
#define BK 64

// GEMM staging/compute shared macro (flat, no templates/lambdas — R8/R9's
// templated core coincided with two container deaths; flat version runs).
// Pipeline: double-buffered LDS + prefetch-next-before-compute, one
// vmcnt-draining __syncthreads per tile (T3 minimum recipe).
// Swizzle (rule #21): linear gload_lds dest, inverse-swizzled global
// SOURCE column, same XOR on the ds_read slot -> 2 lanes/bank = free
// (verified R10: SQ_LDS_BANK_CONFLICT 3.8e7 -> 0).
#define GEMM_PRE(Aptr, aR0, Bptr, bR0, Kdim)                                  \
    __shared__ alignas(16) u16 As[2][BM * BK];                                \
    __shared__ alignas(16) u16 Bs[2][BM * BK];                                \
    int tid = threadIdx.x;                                                    \
    int lane = tid & 63;                                                      \
    int quad = lane >> 4, l16 = lane & 15;                                    \
    int wm = (tid >> 6) & 1, wn = tid >> 7;                                   \
    const u16* aSrc[4];                                                       \
    const u16* bSrc[4];                                                       \
    int ldst[4];                                                              \
    for (int p = 0; p < 4; p++) {                                             \
        int idx = (p << 8) + tid;                                             \
        int r = idx >> 3, sl = idx & 7;                                       \
        int sc = (sl ^ (r & 7)) << 3;                                         \
        aSrc[p] = &(Aptr)[((aR0) + r) * (Kdim) + sc];                         \
        bSrc[p] = &(Bptr)[((bR0) + r) * (Kdim) + sc];                         \
        ldst[p] = idx << 3;                                                   \
    }                                                                         \
    f32x4 acc[4][4];                                                          \
    for (int i = 0; i < 4; i++)                                               \
        for (int j = 0; j < 4; j++) acc[i][j] = (f32x4){0.f, 0.f, 0.f, 0.f};  \
    for (int p = 0; p < 4; p++) {                                             \
        cp16(aSrc[p], &As[0][ldst[p]]);                                       \
        cp16(bSrc[p], &Bs[0][ldst[p]]);                                       \
        aSrc[p] += BK; bSrc[p] += BK;                                         \
    }                                                                         \
    __syncthreads();                                                          \
    int NT = (Kdim) / BK;                                                     \
    int cur = 0;                                                              \
    for (int t = 0; t < NT; ++t) {                                            \
        if (t + 1 < NT) {                                                     \
            for (int p = 0; p < 4; p++) {                                     \
                cp16(aSrc[p], &As[cur ^ 1][ldst[p]]);                         \
                cp16(bSrc[p], &Bs[cur ^ 1][ldst[p]]);                         \
                aSrc[p] += BK; bSrc[p] += BK;                                 \
            }                                                                 \
        }                                                                     \
        _Pragma("unroll")                                                     \
        for (int kk = 0; kk < 2; kk++) {                                      \
            int sA = ((kk * 4 + quad) ^ (l16 & 7)) << 3;                      \
            bf16x8 af[4], bfr[4];                                             \
            _Pragma("unroll")                                                 \
            for (int i = 0; i < 4; i++)                                       \
                af[i] = *(const bf16x8*)&As[cur][(wm * 64 + i * 16 + l16) * 64 + sA]; \
            _Pragma("unroll")                                                 \
            for (int j = 0; j < 4; j++)                                       \
                bfr[j] = *(const bf16x8*)&Bs[cur][(wn * 64 + j * 16 + l16) * 64 + sA]; \
            _Pragma("unroll")                                                 \
            for (int i = 0; i < 4; i++)                                       \
                _Pragma("unroll")                                             \
                for (int j = 0; j < 4; j++)                                   \
                    acc[i][j] = mfma16(af[i], bfr[j], acc[i][j]);             \
        }                                                                     \
        __syncthreads();                                                      \
        cur ^= 1;                                                             \
    }

// ---------------- fused QKV GEMM: one launch, grid (48, 32) -----------------
// B = [WqT; WkT; WvT] stacked (6144x2048). mat: 0->Qb, 1->Kb, 2->Vt (f16,
// per-head transposed [b][h][d][s]).
__global__ __launch_bounds__(256) void gemm_qkv(const u16* __restrict__ A,
                                                const u16* __restrict__ Wcat,
                                                u16* __restrict__ Qb,
                                                u16* __restrict__ Kb,
                                                u16* __restrict__ Vt) {
    long rowBase = (long)blockIdx.y * BM;
    long colG = (long)blockIdx.x * BN;   // 0..6143
    int mat = (int)(colG >> 11);
    long colBase = colG & (DM - 1);
    GEMM_PRE(A, rowBase, Wcat, colG, DM)
    #pragma unroll
    for (int i = 0; i < 4; i++) {
        #pragma unroll
        for (int j = 0; j < 4; j++) {
            long col = colBase + wn * 64 + j * 16 + l16;
            if (mat == 2) {
                long row0 = rowBase + wm * 64 + i * 16 + quad * 4;
                long bb = row0 >> 11, ss = row0 & (SEQ - 1);
                long hh = col >> 7, dd = col & (HD - 1);
                u16x4 pk;
                #pragma unroll
                for (int r = 0; r < 4; r++) pk[r] = f2h(acc[i][j][r]);
                *(u16x4*)&Vt[(((bb * NH) + hh) * HD + dd) * SEQ + ss] = pk;
            } else {
                u16* C = (mat == 0) ? Qb : Kb;
                #pragma unroll
                for (int r = 0; r < 4; r++) {
                    long row = rowBase + wm * 64 + i * 16 + quad * 4 + r;
                    C[row * DM + col] = f2bf(acc[i][j][r]);
                }
            }
        }
    }
}

// ---------------- final GEMM: out(fp32) = Attn(bf16) * WoT^T ----------------
__global__ __launch_bounds__(256) void gemm_out(const u16* __restrict__ A,
                                                const u16* __restrict__ Bt,
                                                float* __restrict__ C) {
    long rowBase = (long)blockIdx.y * BM;
    long colBase = (long)blockIdx.x * BN;
    GEMM_PRE(A, rowBase, Bt, colBase, DM)
    #pragma unroll
    for (int i = 0; i < 4; i++)
        #pragma unroll
        for (int j = 0; j < 4; j++) {
            long col = colBase + wn * 64 + j * 16 + l16;
            #pragma unroll
            for (int r = 0; r < 4; r++) {
                long row = rowBase + wm * 64 + i * 16 + quad * 4 + r;
                C[row * DM + col] = acc[i][j][r];
            }
        }
}

// ---------------- RoPE (in-place on Q and K), fp32 fast trig ----------------
__global__ __launch_bounds__(256) void rope_kernel(u16* __restrict__ Q,
                                                   u16* __restrict__ Kb,
                                                   const int* __restrict__ pid) {
    int idx = blockIdx.x * blockDim.x + threadIdx.x;  // (m, h, d<64)
    int d = idx & 63;
    int h = (idx >> 6) & (NH - 1);
    int m = idx >> 10;  // 0..B*S-1
    int b = m >> 11, s = m & (SEQ - 1);
    int pos = pid[b * SEQ + s];
    float invf = __builtin_amdgcn_exp2f(-(float)d * 0.20762050593046015f);  // log2(10000)/64
    float freq = (float)pos * invf;
    float sn = __sinf(freq);
    float cs = __cosf(freq);
    long base = (long)m * DM + h * HD + d;
    float x1 = bf2f(Q[base]), x2 = bf2f(Q[base + 64]);
    Q[base] = f2bf(x1 * cs - x2 * sn);
    Q[base + 64] = f2bf(x2 * cs + x1 * sn);
    float y1 = bf2f(Kb[base]), y2 = bf2f(Kb[base + 64]);
    Kb[base] = f2bf(y1 * cs - y2 * sn);
    Kb[base + 64] = f2bf(y2 * cs + y1 * sn);
}

// ---------------- MFMA flash attention, kv-split-2 (R10 structure) ----------
// Grid: (BATCH*NH, SEQ/32), 128-thread blocks (2 waves). Both waves own the
// SAME 32 q rows; kv tiles (64 wide) split even/odd. Fixed-offset softmax
// makes partials ADDITIVE; combine = summation via LDS. NO min-waves clause
// (R6: forcing occupancy capped VGPR at 64 -> 0.9 GB spill). kv-split-4
// (R11) regressed: block-wide combine tail + worse per-wave amortization.
// NEW: full-tile fast path — tiles entirely below the causal diagonal with
// all-valid mask (wave-uniform vote) skip the per-element compare/select
// chain (~100 VALU insts/tile); values are bit-identical.
__global__ __launch_bounds__(128) void attn_mfma(const u16* __restrict__ Q,
                                                 const u16* __restrict__ K,
                                                 const u16* __restrict__ Vt,
                                                 const int* __restrict__ amask,
                                                 u16* __restrict__ O) {
    // smem: per-wave P tiles (2 x 4608 B) overlaid (after barrier) by the
    // combine buffers: of_lds 64 lanes x 68 f32 (17408 B) + ls 2048 B.
    __shared__ alignas(16) char smem[19456];
    int tid = threadIdx.x;
    int w = tid >> 6, lane = tid & 63;
    int quad = lane >> 4, l16 = lane & 15;
    int bh = blockIdx.x;
    int qblk = gridDim.y - 1 - blockIdx.y;  // heavy blocks first
    int b = bh >> 4, h = bh & (NH - 1);
    int qbase = qblk * 32;
    long head = (long)b * SEQ * DM + (long)h * HD;
    const u16* Vh = Vt + (long)bh * HD * SEQ;
    const int* mrow = amask + b * SEQ;
    u16* Pw = (u16*)smem + w * (32 * 72);

    bf16x8 qf[2][4];
    #pragma unroll
    for (int i = 0; i < 2; i++)
        #pragma unroll
        for (int kk = 0; kk < 4; kk++)
            qf[i][kk] = *(const bf16x8*)&Q[head + (long)(qbase + i * 16 + l16) * DM + kk * 32 + quad * 8];

    f32x4 of[2][8];
    #pragma unroll
    for (int i = 0; i < 2; i++)
        #pragma unroll
        for (int j = 0; j < 8; j++) of[i][j] = (f32x4){0.f, 0.f, 0.f, 0.f};
    float lsum[2][4] = {{0.f, 0.f, 0.f, 0.f}, {0.f, 0.f, 0.f, 0.f}};
    const float k2 = 0.12752792143808157f;   // (1/sqrt(128)) * log2(e)
    const float C2 = 7.213475204444817f;     // 5 * log2(e)

    int ntiles = (qbase + 32 + 63) >> 6;  // ceil((qbase+32)/64)
    for (int t = w; t < ntiles; t += 2) {
        int kv0 = t << 6;
        bf16x8 kf[16];
        #pragma unroll
        for (int half = 0; half < 4; half++)
            #pragma unroll
            for (int kk = 0; kk < 4; kk++)
                kf[half * 4 + kk] = *(const bf16x8*)&K[head + (long)(kv0 + half * 16 + l16) * DM + kk * 32 + quad * 8];
        int am[4];
        #pragma unroll
        for (int half = 0; half < 4; half++) am[half] = mrow[kv0 + half * 16 + l16];
        f32x4 sacc[2][4];
        #pragma unroll
        for (int i = 0; i < 2; i++)
            #pragma unroll
            for (int half = 0; half < 4; half++) sacc[i][half] = (f32x4){0.f, 0.f, 0.f, 0.f};
        __builtin_amdgcn_s_setprio(1);
        #pragma unroll
        for (int half = 0; half < 4; half++)
            #pragma unroll
            for (int kk = 0; kk < 4; kk++) {
                sacc[0][half] = mfma16(qf[0][kk], kf[half * 4 + kk], sacc[0][half]);
                sacc[1][half] = mfma16(qf[1][kk], kf[half * 4 + kk], sacc[1][half]);
            }
        __builtin_amdgcn_s_setprio(0);
        // ---- softmax numerators; wave-uniform full-tile fast path ----
        bool full = (kv0 + 63 <= qbase) &&
                    __all(am[0] > 0 && am[1] > 0 && am[2] > 0 && am[3] > 0);
        if (full) {
            #pragma unroll
            for (int i = 0; i < 2; i++)
                #pragma unroll
                for (int half = 0; half < 4; half++)
                    #pragma unroll
                    for (int r = 0; r < 4; r++) {
                        float p = __builtin_amdgcn_exp2f(sacc[i][half][r] * k2 - C2);
                        lsum[i][r] += p;
                        Pw[(i * 16 + quad * 4 + r) * 72 + half * 16 + l16] = f2h(p);
                    }
        } else {
            #pragma unroll
            for (int i = 0; i < 2; i++)
                #pragma unroll
                for (int half = 0; half < 4; half++) {
                    int kvc = kv0 + half * 16 + l16;
                    #pragma unroll
                    for (int r = 0; r < 4; r++) {
                        int qr = qbase + i * 16 + quad * 4 + r;
                        float p = (kvc <= qr && am[half] > 0)
                                      ? __builtin_amdgcn_exp2f(sacc[i][half][r] * k2 - C2) : 0.f;
                        lsum[i][r] += p;
                        Pw[(i * 16 + quad * 4 + r) * 72 + half * 16 + l16] = f2h(p);
                    }
                }
        }
        f16x8 pf[2][2];
        #pragma unroll
        for (int i = 0; i < 2; i++)
            #pragma unroll
            for (int c = 0; c < 2; c++)
                pf[i][c] = *(const f16x8*)&Pw[(i * 16 + l16) * 72 + c * 32 + quad * 8];
        __builtin_amdgcn_s_setprio(1);
        #pragma unroll
        for (int c = 0; c < 2; c++)
            #pragma unroll
            for (int j = 0; j < 8; j++) {
                f16x8 vf = *(const f16x8*)&Vh[(long)(j * 16 + l16) * SEQ + kv0 + c * 32 + quad * 8];
                of[0][j] = mfma16h(pf[0][c], vf, of[0][j]);
                of[1][j] = mfma16h(pf[1][c], vf, of[1][j]);
            }
        __builtin_amdgcn_s_setprio(0);
    }
    // ---- combine the two waves' additive partials ----
    __syncthreads();  // both waves done with Pw (LDS about to be reused)
    float* of_lds = (float*)smem;
    float* ls_lds = (float*)(smem + 17408);
    if (w == 1) {
        #pragma unroll
        for (int i = 0; i < 2; i++)
            #pragma unroll
            for (int j = 0; j < 8; j++)
                *(f32x4*)&of_lds[lane * 68 + (i * 8 + j) * 4] = of[i][j];
        #pragma unroll
        for (int i = 0; i < 2; i++)
            #pragma unroll
            for (int r = 0; r < 4; r++) ls_lds[lane * 8 + i * 4 + r] = lsum[i][r];
    }
    __syncthreads();
    if (w == 0) {
        #pragma unroll
        for (int i = 0; i < 2; i++)
            #pragma unroll
            for (int j = 0; j < 8; j++) {
                f32x4 v = *(const f32x4*)&of_lds[lane * 68 + (i * 8 + j) * 4];
                of[i][j] += v;
            }
        #pragma unroll
        for (int i = 0; i < 2; i++)
            #pragma unroll
            for (int r = 0; r < 4; r++) lsum[i][r] += ls_lds[lane * 8 + i * 4 + r];
        #pragma unroll
        for (int i = 0; i < 2; i++) {
            float inv[4];
            #pragma unroll
            for (int r = 0; r < 4; r++) {
                float s = lsum[i][r];
                s += __shfl_xor(s, 1, 64);
                s += __shfl_xor(s, 2, 64);
                s += __shfl_xor(s, 4, 64);
                s += __shfl_xor(s, 8, 64);
                inv[r] = 1.0f / s;
            }
            #pragma unroll
            for (int j = 0; j < 8; j++)
                #pragma unroll
                for (int r = 0; r < 4; r++)
                    O[head + (long)(qbase + i * 16 + quad * 4 + r) * DM + j * 16 + l16] =
                        f2bf(of[i][j][r] * inv[r]);
        }
    }
}

extern "C" void kernel_launch(void* const* d_in, const int* in_sizes, int n_in,
                              void* d_out, int out_size, void* d_ws, size_t ws_size,
                              hipStream_t stream) {
    const float* X  = (const float*)d_in[0];
    const int* am   = (const int*)d_in[1];
    const int* pid  = (const int*)d_in[2];
    const float* Wq = (const float*)d_in[3];
    const float* Wk = (const float*)d_in[4];
    const float* Wv = (const float*)d_in[5];
    const float* Wo = (const float*)d_in[6];
    float* out = (float*)d_out;  // fp32 output, 32 MB

    // Workspace, 64 MB:
    //   [ 0- 8) WoT   [ 8-16) WqT   [16-24) WkT   [24-32) WvT  (contiguous
    //   stack = 6144x2048 B matrix for the fused QKV gemm)
    //   [32-48) Qb (attn output in-place)   [48-64) Kb
    // d_out (32 MB) doubles as scratch until the final gemm:
    //   Xb (bf16 X) at d_out[0:16MB); Vt (f16 [B][H][HD][S]) at [16:32MB).
    char* ws = (char*)d_ws;
    const size_t MB = 1024 * 1024;
    u16* WoT = (u16*)(ws + 0 * MB);
    u16* WqT = (u16*)(ws + 8 * MB);   // Wcat base (WkT, WvT follow)
    u16* WkT = (u16*)(ws + 16 * MB);
    u16* WvT = (u16*)(ws + 24 * MB);
    u16* Qb  = (u16*)(ws + 32 * MB);
    u16* Kb  = (u16*)(ws + 48 * MB);
    u16* Xb  = (u16*)d_out;
    u16* Vt  = (u16*)((char*)d_out + 16 * MB);

    dim3 tb(256);
    prep<<<dim3(64, 64, 5), tb, 0, stream>>>(Wq, Wk, Wv, Wo, X, WqT, WkT, WvT, WoT, Xb);

    gemm_qkv<<<dim3(3 * DM / BN, (BATCH * SEQ) / BM), tb, 0, stream>>>(Xb, WqT, Qb, Kb, Vt);

    int nrope = BATCH * SEQ * NH * 64;
    rope_kernel<<<nrope / 256, tb, 0, stream>>>(Qb, Kb, pid);

    dim3 ag(BATCH * NH, SEQ / 32);  // (32, 64): 2048 two-wave blocks
    attn_mfma<<<ag, dim3(128), 0, stream>>>(Qb, Kb, Vt, am, Qb);  // O in-place

    gemm_out<<<dim3(DM / BN, (BATCH * SEQ) / BM), tb, 0, stream>>>(Qb, WoT, out);
}